// Round 7
// baseline (321.898 us; speedup 1.0000x reference)
//
#include <hip/hip_runtime.h>
#include <hip/hip_bf16.h>

// ModulatedConv (StyleGAN2 conv_transpose2d stride=2, K=3) on gfx950.
// out[b,o,y,x] = inv[b,o] * sum_{i,ky,kx} (scale_w*weight[o,i,ky,kx]) * (s[b,i]*x[b,i,h,w])
// Round 9: occupancy push + launch fusion on top of r6 (fragment-packed wTf,
// chunk-major swizzle-baked xmp2, counted-vmcnt 3-buffer pipeline).
//  * A single-buffered with intra-chunk SPLIT prefetch (compute g[0..NGH) ->
//    load A(kc+1) for those taps -> compute rest -> load rest): frees 48 VGPR
//    -> ~164 unified regs -> __launch_bounds__(256,3) = 3 blocks/CU.
//  * prep fused 5 kernels -> 2 (blockIdx-range dispatch): removes ~3 launch
//    serialization gaps of the ~140us non-conv time.

typedef __attribute__((ext_vector_type(8))) short short8;
typedef __attribute__((ext_vector_type(4))) float floatx4;

#define CIN   512
#define COUT  512
#define OW    65
#define NSITE 1089     // 33*33 sites (u,v); out y=2u+py, x=2v+px
#define XSLOT 1312     // 34*34 padded site grid + stage-overrun pad (zeroed)

__device__ __forceinline__ void gload16(const void* g, void* l) {
    __builtin_amdgcn_global_load_lds(
        (const __attribute__((address_space(1))) void*)g,
        (__attribute__((address_space(3))) void*)l, 16, 0, 0);
}

template <int N>
__device__ __forceinline__ void vmwait() {
    asm volatile("s_waitcnt vmcnt(%0)" :: "n"(N) : "memory");
}

// ---- prep device functions ---------------------------------------------

// s[b,i] = (1/16) * dot(w[b,:], lin_w[i,:]) + lin_b[i]   (32 i x 8 slices)
__device__ __forceinline__ void d_s(int blk, int tid,
    const float* __restrict__ w, const float* __restrict__ lin_w,
    const float* __restrict__ lin_b, float* __restrict__ s)
{
    int li = tid >> 3, sl = tid & 7;
    int i  = (blk & 15) * 32 + li;
    int b  = blk >> 4;
    const float* wr = w + b * 512 + sl * 64;
    const float* lr = lin_w + (size_t)i * 512 + sl * 64;
    float acc = 0.f;
#pragma unroll
    for (int d = 0; d < 64; d += 4) {
        float4 a = *(const float4*)(wr + d);
        float4 c = *(const float4*)(lr + d);
        acc += a.x*c.x + a.y*c.y + a.z*c.z + a.w*c.w;
    }
    acc += __shfl_down(acc, 4, 8);
    acc += __shfl_down(acc, 2, 8);
    acc += __shfl_down(acc, 1, 8);
    if (sl == 0) s[b * 512 + i] = acc * 0.0625f + lin_b[i];
}

// q[o,i] = sum_kk weight[o,i,kk]^2 ; wTf fragment-major pack
__device__ __forceinline__ void d_wq(int blk, int tid,
    const float* __restrict__ weight, __hip_bfloat16* __restrict__ wTf,
    float* __restrict__ q)
{
    int idx = blk * 256 + tid;                  // o*512+i, < 262144
    int o = idx >> 9, i = idx & 511;
    const float* p = weight + (size_t)idx * 9;
    float v[9], acc = 0.f;
#pragma unroll
    for (int j = 0; j < 9; ++j) { v[j] = p[j]; acc += v[j] * v[j]; }
    q[idx] = acc;
    const int o32 = o >> 5, a = (o >> 4) & 1;
    const int kc = i >> 5, quad = (i >> 3) & 3;
    const size_t lanepos = ((size_t)(quad * 16 + (o & 15))) * 8 + (i & 7);
#pragma unroll
    for (int t = 0; t < 9; ++t)
        wTf[(((size_t)(t * 16 + o32) * 16 + kc) * 2 + a) * 512 + lanepos] =
            __float2bfloat16(v[t] * (1.0f / 48.0f));
}

// zero halo + overrun pad of xmp2[b][kc]
__device__ __forceinline__ void d_zero(int blk, int tid,
    __hip_bfloat16* __restrict__ xmp2)
{
    int idx = blk * 256 + tid;                  // < 1152*256
    int q4 = idx & 3;
    int t  = idx >> 2;                          // (b*16+kc)*288 + si
    int si = t % 288;
    int bk = t / 288;
    int slot;
    if      (si < 34)  slot = si;
    else if (si < 68)  slot = 33 * 34 + (si - 34);
    else if (si < 100) slot = (si - 68 + 1) * 34;
    else if (si < 132) slot = (si - 100 + 1) * 34 + 33;
    else               slot = 1156 + (si - 132);
    uint4 z = {0u, 0u, 0u, 0u};
    *(uint4*)(xmp2 + ((size_t)bk * XSLOT + slot) * 32 + q4 * 8) = z;
}

// inv[b,o] = 1/sqrt((1/2304) * sum_i s[b,i]^2 q[o,i] + 1e-8)
__device__ __forceinline__ void d_inv(int blk, int tid,
    const float* __restrict__ s, const float* __restrict__ q,
    float* __restrict__ inv)
{
    int lo = tid >> 3, sl = tid & 7;
    int o  = (blk & 15) * 32 + lo;
    int b  = blk >> 4;
    const float* sp = s + b * 512 + sl * 64;
    const float* qp = q + (size_t)o * 512 + sl * 64;
    float acc = 0.f;
#pragma unroll
    for (int i = 0; i < 64; i += 4) {
        float4 sv = *(const float4*)(sp + i);
        float4 qv = *(const float4*)(qp + i);
        acc += sv.x*sv.x*qv.x + sv.y*sv.y*qv.y + sv.z*sv.z*qv.z + sv.w*sv.w*qv.w;
    }
    acc += __shfl_down(acc, 4, 8);
    acc += __shfl_down(acc, 2, 8);
    acc += __shfl_down(acc, 1, 8);
    if (sl == 0)
        inv[b * 512 + o] = 1.0f / sqrtf(acc * (1.0f / 2304.0f) + 1e-8f);
}

// ---- fused prep kernels ------------------------------------------------

__global__ void prep_a(const float* __restrict__ w, const float* __restrict__ lin_w,
                       const float* __restrict__ lin_b, const float* __restrict__ weight,
                       float* __restrict__ s, __hip_bfloat16* __restrict__ wTf,
                       float* __restrict__ q, __hip_bfloat16* __restrict__ xmp2)
{
    int blk = blockIdx.x, tid = threadIdx.x;
    if      (blk < 256)  d_s   (blk,        tid, w, lin_w, lin_b, s);
    else if (blk < 1280) d_wq  (blk - 256,  tid, weight, wTf, q);
    else                 d_zero(blk - 1280, tid, xmp2);
}

// xmp2[b][kc][slot][pos] = bf16(s[b,i]*x[b,i,h,w]) ; slot=(h+1)*34+(w+1),
// pos = ((tw>>3) ^ ((slot>>1)&3))*8 + (tw&7)  (XOR swizzle baked in)
__global__ void prep_b(const float* __restrict__ x, const float* __restrict__ s,
                       const float* __restrict__ q, float* __restrict__ inv,
                       __hip_bfloat16* __restrict__ xmp2)
{
    __shared__ float tile[32][33];
    int blk = blockIdx.x, tid = threadIdx.x;
    if (blk < 256) { d_inv(blk, tid, s, q, inv); return; }
    int id = blk - 256;                 // < 8192
    int kc = id & 15;                   // channel tile of 32 == K-chunk
    int h  = (id >> 4) & 31;
    int b  = id >> 9;
    int tw = tid & 31;
    int ti = tid >> 5;
#pragma unroll
    for (int r = 0; r < 4; ++r) {
        int il = ti + r * 8;
        int i  = kc * 32 + il;
        tile[il][tw] = x[(((size_t)b * 512 + i) * 32 + h) * 32 + tw] * s[b * 512 + i];
    }
    __syncthreads();
#pragma unroll
    for (int r = 0; r < 4; ++r) {
        int wc   = ti + r * 8;
        int slot = (h + 1) * 34 + (wc + 1);
        int pos  = (((tw >> 3) ^ ((slot >> 1) & 3)) << 3) | (tw & 7);
        xmp2[((size_t)(b * 16 + kc) * XSLOT + slot) * 32 + pos] =
            __float2bfloat16(tile[tw][wc]);
    }
}

// ---- main conv kernel --------------------------------------------------
// r6 pipeline (counted vmcnt, 3 LDS buffers, 2 barriers/chunk) with A
// SINGLE-buffered + split prefetch:
//   bar; stage X(kc+2); vmwait(VM); bar;
//   compute g[0..NGH) with A(kc) ; load A(kc+1) taps[0..TH) (WAR-safe);
//   compute g[NGH..NG)           ; load A(kc+1) taps[TH..NT)
// Prefetch distance ~ half chunk (>= L2 latency); regs -48 vs r6.

template <int PY> struct PT;
template <> struct PT<0> {
    static constexpr int NT = 6, NG = 4, NGH = 2, TH = 3;
    static constexpr int TAPL[6] = {0, 1, 2, 6, 7, 8};
    static constexpr int GTS[4]  = {35, 34, 1, 0};
    static constexpr int GSZ[4]  = {2, 1, 2, 1};
    static constexpr int GST[4]  = {0, 2, 3, 5};
    static constexpr int GPX[6]  = {0, 1, 0, 0, 1, 0};
    // per-chunk issue: S(kc+2) 4 ; A(kc+1) 6+6.  prologue: S0 4, S1 4, A0 12.
    static constexpr int VM(int kc) {
        return kc == 0 ? 20 : kc <= 13 ? 32 : kc == 14 ? 28 : 24;
    }
};
template <> struct PT<1> {
    static constexpr int NT = 3, NG = 2, NGH = 1, TH = 2;
    static constexpr int TAPL[3] = {3, 4, 5};
    static constexpr int GTS[2]  = {35, 34};
    static constexpr int GSZ[2]  = {2, 1};
    static constexpr int GST[2]  = {0, 2};
    static constexpr int GPX[3]  = {0, 1, 0};
    // per-chunk issue: S 4 ; A 4+2.  prologue: S0 4, S1 4, A0 6.
    static constexpr int VM(int kc) {
        return kc == 0 ? 14 : kc <= 13 ? 20 : kc == 14 ? 16 : 12;
    }
};

// Macro-expanded pieces: all indices literal/fully-unrolled (SROA-safe).
#define STAGE_X(NB, KCI)                                                   \
    { _Pragma("unroll")                                                    \
      for (int it = 0; it < 4; ++it)                                       \
          gload16(xg[it] + (size_t)(KCI) * (XSLOT * 32),                   \
                  &Xl[(NB) + it * 2048 + wub]); }

#define PREFETCH_A(TLO, THI, KCI)                                          \
    { _Pragma("unroll")                                                    \
      for (int t = (TLO); t < (THI); ++t) {                                \
          Ar[t][0] = *(const short8*)(wtapP[t] + (KCI) * 1024);            \
          Ar[t][1] = *(const short8*)(wtapP[t] + (KCI) * 1024 + 512);      \
      } }

#define COMPUTE_RANGE(CB, GLO, GHI)                                        \
    { _Pragma("unroll")                                                    \
      for (int g = (GLO); g < (GHI); ++g) {                                \
          short8 B0 = *(const short8*)(&Xl[(CB) + boff[g][0]]);            \
          short8 B1 = *(const short8*)(&Xl[(CB) + boff[g][1]]);            \
          short8 B2 = *(const short8*)(&Xl[(CB) + boff[g][2]]);            \
          short8 B3 = *(const short8*)(&Xl[(CB) + boff[g][3]]);            \
          _Pragma("unroll")                                                \
          for (int j = 0; j < T::GSZ[g]; ++j) {                            \
              const int ti = T::GST[g] + j;                                \
              const int px = T::GPX[ti];                                   \
              acc[px][0][0] = __builtin_amdgcn_mfma_f32_16x16x32_bf16(Ar[ti][0], B0, acc[px][0][0], 0, 0, 0); \
              acc[px][1][0] = __builtin_amdgcn_mfma_f32_16x16x32_bf16(Ar[ti][1], B0, acc[px][1][0], 0, 0, 0); \
              acc[px][0][1] = __builtin_amdgcn_mfma_f32_16x16x32_bf16(Ar[ti][0], B1, acc[px][0][1], 0, 0, 0); \
              acc[px][1][1] = __builtin_amdgcn_mfma_f32_16x16x32_bf16(Ar[ti][1], B1, acc[px][1][1], 0, 0, 0); \
              acc[px][0][2] = __builtin_amdgcn_mfma_f32_16x16x32_bf16(Ar[ti][0], B2, acc[px][0][2], 0, 0, 0); \
              acc[px][1][2] = __builtin_amdgcn_mfma_f32_16x16x32_bf16(Ar[ti][1], B2, acc[px][1][2], 0, 0, 0); \
              acc[px][0][3] = __builtin_amdgcn_mfma_f32_16x16x32_bf16(Ar[ti][0], B3, acc[px][0][3], 0, 0, 0); \
              acc[px][1][3] = __builtin_amdgcn_mfma_f32_16x16x32_bf16(Ar[ti][1], B3, acc[px][1][3], 0, 0, 0); \
          }                                                                \
      } }

#define CHUNK(KC, DO_STAGE, DO_A)                                          \
    { asm volatile("s_waitcnt lgkmcnt(0)" ::: "memory");                   \
      __builtin_amdgcn_s_barrier();                                        \
      if (DO_STAGE) STAGE_X((((KC) + 2) % 3) * 8192, (KC) + 2)             \
      vmwait<T::VM(KC)>();                                                 \
      __builtin_amdgcn_s_barrier();                                        \
      __builtin_amdgcn_s_setprio(1);                                       \
      COMPUTE_RANGE(((KC) % 3) * 8192, 0, T::NGH)                          \
      __builtin_amdgcn_s_setprio(0);                                       \
      if (DO_A) PREFETCH_A(0, T::TH, (KC) + 1)                             \
      __builtin_amdgcn_s_setprio(1);                                       \
      COMPUTE_RANGE(((KC) % 3) * 8192, T::NGH, NG)                         \
      __builtin_amdgcn_s_setprio(0);                                       \
      if (DO_A) PREFETCH_A(T::TH, NT, (KC) + 1) }

template <int PY>
__device__ __forceinline__ void conv_body(
    const __hip_bfloat16* __restrict__ wTf,
    const __hip_bfloat16* __restrict__ xmp2,
    const float* __restrict__ inv,
    float* __restrict__ out,
    short* Xl, const int site_tile, const int o_tile, const int b)
{
    using T = PT<PY>;
    constexpr int NT = T::NT, NG = T::NG;

    const int tid  = threadIdx.x;
    const int lane = tid & 63;
    const int wv   = tid >> 6;
    const int wm   = wv & 1;
    const int wn   = wv >> 1;
    const int quad = lane >> 4;
    const int c16  = lane & 15;

    const int s0     = site_tile * 128;
    const int u_base = s0 / 33;
    const int o_base = o_tile * 64;
    const int o32    = o_tile * 2 + wm;

    // A fragment base pointers: wTf[t][o32] block, + lane*8 (contiguous/wave)
    const __hip_bfloat16* wtapP[NT];
#pragma unroll
    for (int t = 0; t < NT; ++t)
        wtapP[t] = wTf + (size_t)(T::TAPL[t] * 16 + o32) * 16384 + lane * 8;

    // B fragment LDS offsets per (ts-group, f); XOR swizzle keyed on GLOBAL slot
    int boff[NG][4];
#pragma unroll
    for (int f = 0; f < 4; ++f) {
        int site = s0 + wn * 64 + f * 16 + c16;
        int u = site / 33;
        int v = site - u * 33;
        int sb = (u - u_base) * 34 + v;
#pragma unroll
        for (int g = 0; g < NG; ++g) {
            int sl = sb + T::GTS[g];
            int sg = sl + u_base * 34;
            boff[g][f] = sl * 32 + ((quad ^ ((sg >> 1) & 3)) << 3);
        }
    }
    // X staging: contiguous 16KB block per (b,kc) from slot u_base*34
    const __hip_bfloat16* xb =
        xmp2 + ((size_t)b * 16 * XSLOT + (size_t)u_base * 34) * 32;
    const __hip_bfloat16* xg[4];
#pragma unroll
    for (int it = 0; it < 4; ++it)
        xg[it] = xb + (size_t)(it * 256 + tid) * 8;
    // wave-uniform LDS staging base (shorts)
    const int wub = (tid & 192) * 8;

    floatx4 acc[2][2][4];
#pragma unroll
    for (int p = 0; p < 2; ++p)
#pragma unroll
        for (int a = 0; a < 2; ++a)
#pragma unroll
            for (int f = 0; f < 4; ++f)
                acc[p][a][f] = (floatx4){0.f, 0.f, 0.f, 0.f};

    short8 Ar[NT][2];

    // prologue: X(0)->buf0, X(1)->buf1, A(0)->Ar
    STAGE_X(0, 0)
    STAGE_X(8192, 1)
    PREFETCH_A(0, NT, 0)

    CHUNK( 0, 1, 1)  CHUNK( 1, 1, 1)  CHUNK( 2, 1, 1)  CHUNK( 3, 1, 1)
    CHUNK( 4, 1, 1)  CHUNK( 5, 1, 1)  CHUNK( 6, 1, 1)  CHUNK( 7, 1, 1)
    CHUNK( 8, 1, 1)  CHUNK( 9, 1, 1)  CHUNK(10, 1, 1)  CHUNK(11, 1, 1)
    CHUNK(12, 1, 1)  CHUNK(13, 1, 1)  CHUNK(14, 0, 1)  CHUNK(15, 0, 0)

    // epilogue: D col(lane&15)->site, row(quad*4+reg)->o; both px write the
    // same output line (x = 2v, 2v+1) -> contiguous 128B per (a,f,r) frag row.
#pragma unroll
    for (int a = 0; a < 2; ++a) {
        const int ob = o_base + wm * 32 + a * 16 + quad * 4;
        float iv[4];
#pragma unroll
        for (int r = 0; r < 4; ++r) iv[r] = inv[b * COUT + ob + r];
#pragma unroll
        for (int f = 0; f < 4; ++f) {
            int site = s0 + wn * 64 + f * 16 + c16;
            if (site < NSITE) {
                int u = site / 33;
                int v = site - u * 33;
                int y = 2 * u + PY;
                if (y < OW) {
                    int x0 = 2 * v;
#pragma unroll
                    for (int r = 0; r < 4; ++r) {
                        size_t oi = ((size_t)(b * COUT + ob + r) * OW + y) * OW + x0;
                        out[oi] = acc[0][a][f][r] * iv[r];
                        if (v < 32)
                            out[oi + 1] = acc[1][a][f][r] * iv[r];
                    }
                }
            }
        }
    }
}

__global__ __launch_bounds__(256, 3)
void conv_main(const __hip_bfloat16* __restrict__ wTf,
               const __hip_bfloat16* __restrict__ xmp2,
               const float* __restrict__ inv,
               float* __restrict__ out)
{
    __shared__ short Xl[24576];   // 48 KB: 3 x (256 slots x 32 k)

    // XCD-chunked swizzle: hw linear id n -> XCD ~ n%8. XCD j gets logical
    // range [j*288,(j+1)*288) = exactly 2 batch slices; within: b outer,
    // o_tile (8), py (2), site (9) inner.
    const int n  = blockIdx.x + 9 * blockIdx.y + 144 * blockIdx.z;
    const int lg = (n & 7) * 288 + (n >> 3);
    const int b  = lg / 144;
    int rem = lg - b * 144;
    const int o_tile = rem / 18;
    rem -= o_tile * 18;
    const int py   = rem / 9;
    const int site = rem - py * 9;

    if (py == 0) conv_body<0>(wTf, xmp2, inv, out, Xl, site, o_tile, b);
    else         conv_body<1>(wTf, xmp2, inv, out, Xl, site, o_tile, b);
}

// ---- launcher ----------------------------------------------------------
extern "C" void kernel_launch(void* const* d_in, const int* in_sizes, int n_in,
                              void* d_out, int out_size, void* d_ws, size_t ws_size,
                              hipStream_t stream)
{
    const float* x      = (const float*)d_in[0];   // (16,512,32,32)
    const float* w      = (const float*)d_in[1];   // (16,512)
    const float* weight = (const float*)d_in[2];   // (1,512,512,3,3)
    const float* lin_w  = (const float*)d_in[3];   // (512,512)
    const float* lin_b  = (const float*)d_in[4];   // (512,)
    float* out = (float*)d_out;                    // (16,512,65,65)

    char* ws = (char*)d_ws;
    float* s_buf   = (float*)(ws);                          //   32 KB
    float* inv_buf = (float*)(ws + 32768);                  //   32 KB
    float* q_buf   = (float*)(ws + 65536);                  //    1 MB
    __hip_bfloat16* wTf  = (__hip_bfloat16*)(ws + 1114112); // 4.72 MB [9][16][16][2][512]
    __hip_bfloat16* xmp2 = (__hip_bfloat16*)(ws + 5832704); // 21.5 MB [16][16][1312][32]

    prep_a<<<2432, 256, 0, stream>>>(w, lin_w, lin_b, weight, s_buf, wTf, q_buf, xmp2);
    prep_b<<<8448, 256, 0, stream>>>(x, s_buf, q_buf, inv_buf, xmp2);
    conv_main<<<dim3(9, 16, 16), 256, 0, stream>>>(wTf, xmp2, inv_buf, out);
}